// Round 6
// baseline (10033.116 us; speedup 1.0000x reference)
//
#include <hip/hip_runtime.h>
#include <stdint.h>

using short8 = __attribute__((ext_vector_type(8))) short;
using f32x4  = __attribute__((ext_vector_type(4))) float;
using uint4v = __attribute__((ext_vector_type(4))) unsigned;
typedef unsigned long long ull;

#define DEV static __device__ __forceinline__

DEV unsigned short f2bf(float f){
  unsigned u = __builtin_bit_cast(unsigned, f);
  u = (u + 0x7FFFu + ((u >> 16) & 1u)) >> 16;
  return (unsigned short)u;
}
DEV float bf2f(unsigned short v){
  return __builtin_bit_cast(float, ((unsigned)v) << 16);
}
DEV float sigm(float x){
  float e = __builtin_amdgcn_exp2f(-1.4426950408889634f * x);
  return __builtin_amdgcn_rcpf(1.0f + e);
}
DEV float tanh_(float x){
  float e = __builtin_amdgcn_exp2f(2.885390081777927f * x); // exp(2x)
  return 1.0f - 2.0f * __builtin_amdgcn_rcpf(e + 1.0f);
}

// LDS-only barriers: no vmcnt drain (keeps out-store/prefetch acks off the
// critical path). lgkmcnt(0) orders ds_write visibility; sched_barrier pins
// (rule #18: compiler hoists non-memory ops past inline-asm waitcnt).
DEV void bar_lds(){
  __builtin_amdgcn_sched_barrier(0);
  asm volatile("s_waitcnt lgkmcnt(0)" ::: "memory");
  __builtin_amdgcn_s_barrier();
  __builtin_amdgcn_sched_barrier(0);
}
DEV void bar_plain(){
  __builtin_amdgcn_sched_barrier(0);
  __builtin_amdgcn_s_barrier();
  __builtin_amdgcn_sched_barrier(0);
}

// fragment readiness: 4 ull = 8 tagged units; all tags must equal `pat` slots
DEV int frag_ok(const ull d0, const ull d1, const ull d2, const ull d3, ull pat){
  const ull M = 0xFFFF0000FFFF0000ull;
  ull v = ((d0 & M) ^ pat) | ((d1 & M) ^ pat) | ((d2 & M) ^ pat) | ((d3 & M) ^ pat);
  return __all(v == 0);
}
DEV short8 unpack_h(const ull d0, const ull d1, const ull d2, const ull d3){
  uint4v u;
  u[0] = (unsigned)(d0 & 0xFFFFull) | ((unsigned)(d0 >> 32) << 16);
  u[1] = (unsigned)(d1 & 0xFFFFull) | ((unsigned)(d1 >> 32) << 16);
  u[2] = (unsigned)(d2 & 0xFFFFull) | ((unsigned)(d2 >> 32) << 16);
  u[3] = (unsigned)(d3 & 0xFFFFull) | ((unsigned)(d3 >> 32) << 16);
  return __builtin_bit_cast(short8, u);
}

// ---------------- aux kernels ----------------

__global__ void k_f32_to_bf16(const float* __restrict__ in, unsigned short* __restrict__ out, int n){
  int stride = gridDim.x * blockDim.x * 4;
  for (int i = (blockIdx.x * blockDim.x + threadIdx.x) * 4; i < n; i += stride){
    float4 v = *(const float4*)(in + i);
    ushort4 o4;
    o4.x = f2bf(v.x); o4.y = f2bf(v.y); o4.z = f2bf(v.z); o4.w = f2bf(v.w);
    *(ushort4*)(out + i) = o4;
  }
}

// bf16 + bf16 -> bf16 (enc fwd+bwd sum)
__global__ void k_add_bb(const unsigned short* __restrict__ a, const unsigned short* __restrict__ b,
                         unsigned short* __restrict__ out, int n){
  int stride = gridDim.x * blockDim.x * 8;
  for (int i = (blockIdx.x * blockDim.x + threadIdx.x) * 8; i < n; i += stride){
    short8 va = *(const short8*)(a + i);
    short8 vb = *(const short8*)(b + i);
    short8 o;
    #pragma unroll
    for (int j = 0; j < 8; ++j)
      o[j] = (short)f2bf(bf2f((unsigned short)va[j]) + bf2f((unsigned short)vb[j]));
    *(short8*)(out + i) = o;
  }
}

__global__ void k_add_f32(float* __restrict__ o, const float* __restrict__ b, int n){
  int stride = gridDim.x * blockDim.x * 4;
  for (int i = (blockIdx.x * blockDim.x + threadIdx.x) * 4; i < n; i += stride){
    float4 vo = *(const float4*)(o + i);
    float4 vb = *(const float4*)(b + i);
    vo.x += vb.x; vo.y += vb.y; vo.z += vb.z; vo.w += vb.w;
    *(float4*)(o + i) = vo;
  }
}

// Pack [k; r] (f32, [K,4U] each, K split KX|U) into per-(dir,wg,wave,ktile,ntile)
// B-fragment order. K-tiles INTERLEAVED across waves: global_kt = kt*4 + w,
// so every wave gets an equal x/h mix (balanced load + latency hiding).
__global__ void k_pack(const float* __restrict__ k0, const float* __restrict__ r0,
                       const float* __restrict__ k1, const float* __restrict__ r1,
                       unsigned short* __restrict__ out, int E, int KX, int U){
  int n = 2 * E;
  int stride = gridDim.x * blockDim.x;
  for (int i = blockIdx.x * blockDim.x + threadIdx.x; i < n; i += stride){
    int d = i / E, r = i % E;
    const float* Km = d ? k1 : k0;
    const float* Rm = d ? r1 : r0;
    int j    = r & 7;  int q = r >> 3;
    int lane = q & 63; q >>= 6;
    int nt   = q & 3;  q >>= 2;
    int kt   = q % 6;  q /= 6;
    int w    = q & 3;  int wg = q >> 2;
    int k    = (kt*4 + w)*32 + ((lane >> 4) << 3) + j;   // interleaved K split
    int col  = nt * U + wg*16 + (lane & 15);             // gate-major column
    float v  = (k < KX) ? Km[(size_t)k * (4*U) + col]
                        : Rm[(size_t)(k - KX) * (4*U) + col];
    out[i] = f2bf(v);
  }
}

// ---------------- persistent recurrence kernel ----------------
// h exchange: TAGGED units. hb2[par][row][unit] is u32 = bf16(h) | (step<<16).
// Producers publish with fire-and-forget agent-scope b32 atomic stores
// (no ack wait, no counter, no barrier on the publish path). Consumers
// load b64 pairs and check the in-data tags: readiness and data arrive in
// the SAME round trip. Batched retry reloads all stale fragments at once.
// Skew safety: all-to-all unit dependence bounds WG skew to <=1 step, and
// slots are rewritten only 2 steps later. Replay safety: h is bit-identical
// across graph replays, so any stale tag carries the correct value.
// OBF: bf16 outputs (encoder) vs f32 (decoder).
template<int KX, int U, int WGS, bool OBF>
__global__ __launch_bounds__(256, 1)
void lstm_rec(const unsigned short* __restrict__ xab,    // [64][512][KX] bf16
              const unsigned short* __restrict__ packedB,
              const float* __restrict__ bias_f,
              const float* __restrict__ bias_b,
              const int*   __restrict__ sizes,
              unsigned* __restrict__ hbuf2,              // [2 dirs][2 par][64][U] u32
              void* __restrict__ out_f,                  // [64][512][U]
              void* __restrict__ out_b)
{
  constexpr int KTW = 6;             // K tiles per wave
  constexpr int XKT = KX / 128;      // x tiles per wave (interleaved split)
  constexpr int NH  = KTW - XKT;     // h tiles per wave
  constexpr int T   = 512;

  const int tid  = threadIdx.x;
  const int w    = tid >> 6;
  const int lane = tid & 63;
  const int dir  = (blockIdx.x >= WGS) ? 1 : 0;
  const int wg   = dir ? (int)blockIdx.x - WGS : (int)blockIdx.x;

  const unsigned short* pB = packedB + (size_t)dir * ((size_t)WGS*4*KTW*4*512)
                                     + (size_t)((wg*4 + w)*KTW)*4*512;
  unsigned* hb2     = hbuf2 + (size_t)dir * (2*64*U);
  const float* bias = dir ? bias_b : bias_f;
  void* outp        = dir ? out_b : out_f;

  // preload B fragments (step-invariant): 96 VGPRs
  short8 bfr[KTW][4];
  #pragma unroll
  for (int kt = 0; kt < KTW; ++kt)
    #pragma unroll
    for (int nt = 0; nt < 4; ++nt)
      bfr[kt][nt] = *(const short8*)(pB + ((kt*4 + nt)*512) + lane*8);

  // gate-phase ownership: unit u_l (0..15), rows rb..rb+3
  const int u_l = tid & 15;
  const int rb  = (tid >> 4) * 4;
  const int ug  = wg*16 + u_l;
  float bz[4]; int sz[4];
  #pragma unroll
  for (int g = 0; g < 4; ++g) bz[g] = bias[g*U + ug];
  #pragma unroll
  for (int r = 0; r < 4; ++r) sz[r] = sizes[rb + r];
  float c[4]    = {0.f,0.f,0.f,0.f};
  float hreg[4] = {0.f,0.f,0.f,0.f};

  // [wave][zcol 64][row 64 + pad]; scatter and gate reads both b128
  __shared__ float part[4][64][68];

  const int arow  = lane & 15;         // A-frag row / D-frag col within tile
  const int kgrp  = (lane >> 4) * 8;   // A-frag k offset within ktile
  const int rquad = (lane >> 4) * 4;   // D-frag row base

  // x fragments, prefetched one step ahead
  short8 xreg[XKT][4];
  {
    const int t0 = dir ? T - 1 : 0;
    #pragma unroll
    for (int kt = 0; kt < XKT; ++kt){
      const int kg = (kt*4 + w) * 32;
      #pragma unroll
      for (int mt = 0; mt < 4; ++mt)
        xreg[kt][mt] = *(const short8*)(xab + ((size_t)((mt*16 + arow)*T + t0))*KX + (kg + kgrp));
    }
  }

  ull raw[NH][4][4];   // tagged h loads: [h-tile][mt][4 x b64]

  for (int s = 0; s < T; ++s){
    const int t   = dir ? (T - 1 - s) : s;
    const int par = s & 1;
    const ull tag = (ull)(unsigned)s;
    const ull pat = (tag << 16) | (tag << 48);
    const unsigned* hb2r = hb2 + (size_t)par*64*U;

    // ---- A: early-issue h loads (first poll attempt) ----
    if (s > 0){
      #pragma unroll
      for (int i = 0; i < NH; ++i){
        const int hu = ((XKT + i)*4 + w)*32 - KX + kgrp;
        #pragma unroll
        for (int mt = 0; mt < 4; ++mt){
          const ull* hp = (const ull*)(hb2r + (size_t)(mt*16 + arow)*U + hu);
          #pragma unroll
          for (int j = 0; j < 4; ++j)
            raw[i][mt][j] = __hip_atomic_load(hp + j, __ATOMIC_RELAXED, __HIP_MEMORY_SCOPE_AGENT);
        }
      }
    }

    f32x4 acc[4][4];
    #pragma unroll
    for (int mt = 0; mt < 4; ++mt)
      #pragma unroll
      for (int nt = 0; nt < 4; ++nt)
        acc[mt][nt] = (f32x4){0.f, 0.f, 0.f, 0.f};

    // ---- B: x MFMAs (no cross-WG dependence; hides h-load latency) ----
    #pragma unroll
    for (int kt = 0; kt < XKT; ++kt)
      #pragma unroll
      for (int mt = 0; mt < 4; ++mt)
        #pragma unroll
        for (int nt = 0; nt < 4; ++nt)
          acc[mt][nt] = __builtin_amdgcn_mfma_f32_16x16x32_bf16(xreg[kt][mt], bfr[kt][nt], acc[mt][nt], 0, 0, 0);

    if (s > 0){
      // ---- C: batched tag-check / retry ----
      unsigned bad = (1u << (NH*4)) - 1u;
      for (;;){
        unsigned nbad = 0;
        #pragma unroll
        for (int i = 0; i < NH; ++i)
          #pragma unroll
          for (int mt = 0; mt < 4; ++mt){
            const unsigned f = i*4 + mt;
            if (bad & (1u << f))
              if (!frag_ok(raw[i][mt][0], raw[i][mt][1], raw[i][mt][2], raw[i][mt][3], pat))
                nbad |= 1u << f;
          }
        if (!nbad) break;
        #pragma unroll
        for (int i = 0; i < NH; ++i){
          const int hu = ((XKT + i)*4 + w)*32 - KX + kgrp;
          #pragma unroll
          for (int mt = 0; mt < 4; ++mt){
            const unsigned f = i*4 + mt;
            if (nbad & (1u << f)){
              const ull* hp = (const ull*)(hb2r + (size_t)(mt*16 + arow)*U + hu);
              #pragma unroll
              for (int j = 0; j < 4; ++j)
                raw[i][mt][j] = __hip_atomic_load(hp + j, __ATOMIC_RELAXED, __HIP_MEMORY_SCOPE_AGENT);
            }
          }
        }
        bad = nbad;
      }
      // ---- D: unpack + h MFMAs ----
      #pragma unroll
      for (int i = 0; i < NH; ++i)
        #pragma unroll
        for (int mt = 0; mt < 4; ++mt){
          short8 a = unpack_h(raw[i][mt][0], raw[i][mt][1], raw[i][mt][2], raw[i][mt][3]);
          #pragma unroll
          for (int nt = 0; nt < 4; ++nt)
            acc[mt][nt] = __builtin_amdgcn_mfma_f32_16x16x32_bf16(a, bfr[XKT + i][nt], acc[mt][nt], 0, 0, 0);
        }
    }

    // ---- bar2: previous step's gate reads done before scatter overwrites ----
    bar_plain();

    // ---- E: D-frag scatter: col = lane&15 (zcol), rows rquad..+3 -> b128 ----
    #pragma unroll
    for (int mt = 0; mt < 4; ++mt)
      #pragma unroll
      for (int nt = 0; nt < 4; ++nt)
        *(f32x4*)&part[w][nt*16 + arow][mt*16 + rquad] = acc[mt][nt];

    // ---- bar1: LDS-only visibility barrier (no vmcnt drain) ----
    bar_lds();

    // ---- G: gate phase ----
    f32x4 zg[4];
    #pragma unroll
    for (int g = 0; g < 4; ++g){
      const int cb = g*16 + u_l;
      f32x4 v = *(const f32x4*)&part[0][cb][rb];
      #pragma unroll
      for (int ww = 1; ww < 4; ++ww)
        v += *(const f32x4*)&part[ww][cb][rb];
      zg[g] = v;
    }

    unsigned* hb2w = hb2 + (size_t)(par ^ 1)*64*U;
    const unsigned utag = (unsigned)(s + 1) << 16;
    #pragma unroll
    for (int r = 0; r < 4; ++r){
      float ig = sigm (zg[0][r] + bz[0]);
      float fg = sigm (zg[1][r] + bz[1]);
      float gg = tanh_(zg[2][r] + bz[2]);
      float og = sigm (zg[3][r] + bz[3]);
      float cn = fg * c[r] + ig * gg;
      float hn = og * tanh_(cn);
      bool m  = (t < sz[r]);
      c[r] = m ? cn : c[r];
      float h = m ? hn : hreg[r];
      hreg[r] = h;
      // ---- H: tagged publish, fire-and-forget ----
      if (s != T - 1)
        __hip_atomic_store(hb2w + (size_t)(rb + r)*U + ug,
                           (unsigned)f2bf(h) | utag,
                           __ATOMIC_RELAXED, __HIP_MEMORY_SCOPE_AGENT);
      // out store (ack overlaps next step's poll)
      const size_t oi = ((size_t)(rb + r)*T + t)*U + ug;
      if constexpr (OBF) ((unsigned short*)outp)[oi] = f2bf(h);
      else               ((float*)outp)[oi] = h;
    }

    // ---- I: x prefetch for next step ----
    if (s != T - 1){
      const int tn = dir ? t - 1 : t + 1;
      #pragma unroll
      for (int kt = 0; kt < XKT; ++kt){
        const int kg = (kt*4 + w) * 32;
        #pragma unroll
        for (int mt = 0; mt < 4; ++mt)
          xreg[kt][mt] = *(const short8*)(xab + ((size_t)((mt*16 + arow)*T + tn))*KX + (kg + kgrp));
      }
    }
  }
}

// ---------------- launch ----------------

extern "C" void kernel_launch(void* const* d_in, const int* in_sizes, int n_in,
                              void* d_out, int out_size, void* d_ws, size_t ws_size,
                              hipStream_t stream){
  const float* x      = (const float*)d_in[0];
  const int*   sizes  = (const int*)  d_in[1];
  const float* enc_kf = (const float*)d_in[2];
  const float* enc_rf = (const float*)d_in[3];
  const float* enc_bf = (const float*)d_in[4];
  const float* enc_kb = (const float*)d_in[5];
  const float* enc_rb = (const float*)d_in[6];
  const float* enc_bb = (const float*)d_in[7];
  const float* dec_kf = (const float*)d_in[8];
  const float* dec_rf = (const float*)d_in[9];
  const float* dec_bf = (const float*)d_in[10];
  const float* dec_kb = (const float*)d_in[11];
  const float* dec_rb = (const float*)d_in[12];
  const float* dec_bb = (const float*)d_in[13];
  float* out = (float*)d_out;
  char*  ws  = (char*)d_ws;

  const size_t o_xbf  = 0;                        // 33,554,432  x bf16 [64][512][512]
  const size_t o_esum = o_xbf  + 33554432ull;     // 16,777,216  enc fwd+bwd sum bf16
  const size_t o_pBe  = o_esum + 16777216ull;     //  3,145,728  packed enc [k;r]
  const size_t o_pBd  = o_pBe  + 3145728ull;      //  6,291,456  packed dec [k;r]
  const size_t o_ehf  = o_pBd  + 6291456ull;      // 16,777,216  enc fwd h bf16
  const size_t o_ehb  = o_ehf  + 16777216ull;     // 16,777,216  enc bwd h bf16
  const size_t o_dhb  = o_ehb  + 16777216ull;     // 67,108,864  dec bwd h f32
  const size_t o_hb2e = o_dhb  + 67108864ull;     //    262,144  enc tagged h exchange
  const size_t o_hb2d = o_hb2e + 262144ull;       //    524,288  dec tagged h exchange
  const size_t total  = o_hb2d + 524288ull;       // ~161.2 MB
  if (ws_size < total) return;

  unsigned short* xbf  = (unsigned short*)(ws + o_xbf);
  unsigned short* esum = (unsigned short*)(ws + o_esum);
  unsigned short* pBe  = (unsigned short*)(ws + o_pBe);
  unsigned short* pBd  = (unsigned short*)(ws + o_pBd);
  unsigned short* ehf  = (unsigned short*)(ws + o_ehf);
  unsigned short* ehb  = (unsigned short*)(ws + o_ehb);
  float*          dhb  = (float*)(ws + o_dhb);
  unsigned*       hb2e = (unsigned*)(ws + o_hb2e);
  unsigned*       hb2d = (unsigned*)(ws + o_hb2d);

  // zero h-exchange tags (consumers then wait for fresh publishes; stale
  // tags would also be value-correct across replays, this is belt+braces
  // against first-call garbage)
  hipMemsetAsync(ws + o_hb2e, 0, 262144ull + 524288ull, stream);

  // x -> bf16
  k_f32_to_bf16<<<2048, 256, 0, stream>>>(x, xbf, 64*512*512);

  // pack weights (interleaved K split)
  k_pack<<<2048, 256, 0, stream>>>(enc_kf, enc_rf, enc_kb, enc_rb, pBe, 786432, 512, 256);
  k_pack<<<2048, 256, 0, stream>>>(dec_kf, dec_rf, dec_kb, dec_rb, pBd, 1572864, 256, 512);

  // encoder bilstm (fwd 16 WGs + bwd 16 WGs), bf16 outputs
  lstm_rec<512, 256, 16, true><<<32, 256, 0, stream>>>(xbf, pBe, enc_bf, enc_bb, sizes,
                                                       hb2e, ehf, ehb);
  // enc_sum = bf16(hf + hb)
  k_add_bb<<<2048, 256, 0, stream>>>(ehf, ehb, esum, 64*512*256);

  // decoder bilstm: fwd writes d_out f32, bwd to ws
  lstm_rec<256, 512, 32, false><<<64, 256, 0, stream>>>(esum, pBd, dec_bf, dec_bb, sizes,
                                                        hb2d, out, dhb);
  // d_out += dec bwd
  k_add_f32<<<2048, 256, 0, stream>>>(out, dhb, 64*512*512);
}

// Round 7
// 6771.259 us; speedup vs baseline: 1.4817x; 1.4817x over previous
//
#include <hip/hip_runtime.h>
#include <stdint.h>

using short8 = __attribute__((ext_vector_type(8))) short;
using f32x4  = __attribute__((ext_vector_type(4))) float;
typedef unsigned long long ull;

#define DEV static __device__ __forceinline__

DEV unsigned short f2bf(float f){
  unsigned u = __builtin_bit_cast(unsigned, f);
  u = (u + 0x7FFFu + ((u >> 16) & 1u)) >> 16;
  return (unsigned short)u;
}
DEV float bf2f(unsigned short v){
  return __builtin_bit_cast(float, ((unsigned)v) << 16);
}
DEV float sigm(float x){
  float e = __builtin_amdgcn_exp2f(-1.4426950408889634f * x);
  return __builtin_amdgcn_rcpf(1.0f + e);
}
DEV float tanh_(float x){
  float e = __builtin_amdgcn_exp2f(2.885390081777927f * x); // exp(2x)
  return 1.0f - 2.0f * __builtin_amdgcn_rcpf(e + 1.0f);
}

// LDS-only barrier: no vmcnt drain (HBM/LLC acks stay off the critical path).
DEV void bar_lds(){
  __builtin_amdgcn_sched_barrier(0);
  asm volatile("s_waitcnt lgkmcnt(0)" ::: "memory");
  __builtin_amdgcn_s_barrier();
  __builtin_amdgcn_sched_barrier(0);
}

// ---------------- aux kernels ----------------

__global__ void k_f32_to_bf16(const float* __restrict__ in, unsigned short* __restrict__ out, int n){
  int stride = gridDim.x * blockDim.x * 4;
  for (int i = (blockIdx.x * blockDim.x + threadIdx.x) * 4; i < n; i += stride){
    float4 v = *(const float4*)(in + i);
    ushort4 o4;
    o4.x = f2bf(v.x); o4.y = f2bf(v.y); o4.z = f2bf(v.z); o4.w = f2bf(v.w);
    *(ushort4*)(out + i) = o4;
  }
}

// bf16 + bf16 -> bf16 (enc fwd+bwd sum)
__global__ void k_add_bb(const unsigned short* __restrict__ a, const unsigned short* __restrict__ b,
                         unsigned short* __restrict__ out, int n){
  int stride = gridDim.x * blockDim.x * 8;
  for (int i = (blockIdx.x * blockDim.x + threadIdx.x) * 8; i < n; i += stride){
    short8 va = *(const short8*)(a + i);
    short8 vb = *(const short8*)(b + i);
    short8 o;
    #pragma unroll
    for (int j = 0; j < 8; ++j)
      o[j] = (short)f2bf(bf2f((unsigned short)va[j]) + bf2f((unsigned short)vb[j]));
    *(short8*)(out + i) = o;
  }
}

__global__ void k_add_f32(float* __restrict__ o, const float* __restrict__ b, int n){
  int stride = gridDim.x * blockDim.x * 4;
  for (int i = (blockIdx.x * blockDim.x + threadIdx.x) * 4; i < n; i += stride){
    float4 vo = *(const float4*)(o + i);
    float4 vb = *(const float4*)(b + i);
    vo.x += vb.x; vo.y += vb.y; vo.z += vb.z; vo.w += vb.w;
    *(float4*)(o + i) = vo;
  }
}

// Pack [k; r] (f32, [K,4U] each, K split KX|U) into per-(dir,wg,wave,ktile,ntile)
// MFMA B-fragment order (BLOCKED K split: wave w owns ktiles 6w..6w+5):
// idx = ((((wg*4+w)*6+kt)*4+nt)*64+lane)*8+j
__global__ void k_pack(const float* __restrict__ k0, const float* __restrict__ r0,
                       const float* __restrict__ k1, const float* __restrict__ r1,
                       unsigned short* __restrict__ out, int E, int KX, int U){
  int n = 2 * E;
  int stride = gridDim.x * blockDim.x;
  for (int i = blockIdx.x * blockDim.x + threadIdx.x; i < n; i += stride){
    int d = i / E, r = i % E;
    const float* Km = d ? k1 : k0;
    const float* Rm = d ? r1 : r0;
    int j    = r & 7;  int q = r >> 3;
    int lane = q & 63; q >>= 6;
    int nt   = q & 3;  q >>= 2;
    int kt   = q % 6;  q /= 6;
    int w    = q & 3;  int wg = q >> 2;
    int k    = (w*6 + kt)*32 + ((lane >> 4) << 3) + j;   // blocked K split
    int col  = nt * U + wg*16 + (lane & 15);             // gate-major column
    float v  = (k < KX) ? Km[(size_t)k * (4*U) + col]
                        : Rm[(size_t)(k - KX) * (4*U) + col];
    out[i] = f2bf(v);
  }
}

// ---------------- persistent recurrence kernel ----------------
// Per-step sync protocol (no RMW, no full-WG drain, no cache-maintenance):
//   producer wave: h relaxed agent-atomic stores (sc1 write-through)
//     -> inline s_waitcnt vmcnt(0)  (h acked at LLC; out-stores not yet issued)
//     -> lane0 relaxed flag store on its own 128B line (flg[wg*4+w] = s+1)
//   consumer wave: 64-lane gather of all per-wave flags, __all(v >= s),
//     then bulk b64 h loads (single shot, no data spin).
// part[] double-buffered by parity -> exactly ONE LDS-only barrier per step.
// OBF: bf16 outputs (encoder) vs f32 (decoder).
template<int KX, int U, int WGS, bool OBF>
__global__ __launch_bounds__(256, 1)
void lstm_rec(const unsigned short* __restrict__ xab,    // [64][512][KX] bf16
              const unsigned short* __restrict__ packedB,
              const float* __restrict__ bias_f,
              const float* __restrict__ bias_b,
              const int*   __restrict__ sizes,
              unsigned short* __restrict__ hbuf,         // [2 dirs][2 par][64][U] bf16
              unsigned* __restrict__ flags,              // [2 dirs][WGS*4 * 32]
              void* __restrict__ out_f,                  // [64][512][U]
              void* __restrict__ out_b)
{
  constexpr int KTW = 6;             // K tiles per wave (blocked)
  constexpr int T   = 512;
  constexpr int NF  = WGS * 4;       // per-wave flags per dir (64 or 128)

  const int tid  = threadIdx.x;
  const int w    = tid >> 6;
  const int lane = tid & 63;
  const int dir  = (blockIdx.x >= WGS) ? 1 : 0;
  const int wg   = dir ? (int)blockIdx.x - WGS : (int)blockIdx.x;

  const unsigned short* pB = packedB + (size_t)dir * ((size_t)WGS*4*KTW*4*512)
                                     + (size_t)((wg*4 + w)*KTW)*4*512;
  unsigned short* hb = hbuf + (size_t)dir * (2*64*U);
  unsigned*      flg = flags + (size_t)dir * (NF*32);
  const float* bias  = dir ? bias_b : bias_f;
  void* outp         = dir ? out_b : out_f;

  // does this wave own any h-ktile? (blocked split)
  const bool has_h = ((w*KTW + KTW - 1) * 32) >= KX;

  // preload B fragments (step-invariant): 96 VGPRs
  short8 bfr[KTW][4];
  #pragma unroll
  for (int kt = 0; kt < KTW; ++kt)
    #pragma unroll
    for (int nt = 0; nt < 4; ++nt)
      bfr[kt][nt] = *(const short8*)(pB + ((kt*4 + nt)*512) + lane*8);

  // gate-phase ownership: unit u_l (0..15), rows rb..rb+3
  const int u_l = tid & 15;
  const int rb  = (tid >> 4) * 4;
  const int ug  = wg*16 + u_l;
  float bz[4]; int sz[4];
  #pragma unroll
  for (int g = 0; g < 4; ++g) bz[g] = bias[g*U + ug];
  #pragma unroll
  for (int r = 0; r < 4; ++r) sz[r] = sizes[rb + r];
  float c[4]    = {0.f,0.f,0.f,0.f};
  float hreg[4] = {0.f,0.f,0.f,0.f};

  // parity-double-buffered wave partials: 2 x 4 x 64 x 68 x 4B = 139 KB LDS
  __shared__ float part[2][4][64][68];

  const int arow  = lane & 15;         // A-frag row / D-frag col within tile
  const int kgrp  = (lane >> 4) * 8;   // A-frag k offset within ktile
  const int rquad = (lane >> 4) * 4;   // D-frag row base

  // x fragments, prefetched one step ahead
  short8 xreg[KTW][4];
  {
    const int t0 = dir ? T - 1 : 0;
    #pragma unroll
    for (int kt = 0; kt < KTW; ++kt){
      const int kg = (w*KTW + kt) * 32;
      if (kg < KX){
        #pragma unroll
        for (int mt = 0; mt < 4; ++mt)
          xreg[kt][mt] = *(const short8*)(xab + ((size_t)((mt*16 + arow)*T + t0))*KX + (kg + kgrp));
      }
    }
  }

  for (int s = 0; s < T; ++s){
    const int t   = dir ? (T - 1 - s) : s;
    const int par = s & 1;

    f32x4 acc[4][4];
    #pragma unroll
    for (int mt = 0; mt < 4; ++mt)
      #pragma unroll
      for (int nt = 0; nt < 4; ++nt)
        acc[mt][nt] = (f32x4){0.f, 0.f, 0.f, 0.f};

    // ---- x MFMAs (no cross-WG dependence) ----
    #pragma unroll
    for (int kt = 0; kt < KTW; ++kt){
      const int kg = (w*KTW + kt) * 32;
      if (kg < KX){
        #pragma unroll
        for (int mt = 0; mt < 4; ++mt)
          #pragma unroll
          for (int nt = 0; nt < 4; ++nt)
            acc[mt][nt] = __builtin_amdgcn_mfma_f32_16x16x32_bf16(xreg[kt][mt], bfr[kt][nt], acc[mt][nt], 0, 0, 0);
      }
    }

    if (s > 0 && has_h){
      // ---- poll: one 64-lane gather of per-wave flags ----
      const unsigned tgt = (unsigned)s;
      for (;;){
        unsigned v = __hip_atomic_load(&flg[lane*32], __ATOMIC_RELAXED, __HIP_MEMORY_SCOPE_AGENT);
        if constexpr (NF > 64){
          unsigned v2 = __hip_atomic_load(&flg[(lane + 64)*32], __ATOMIC_RELAXED, __HIP_MEMORY_SCOPE_AGENT);
          v = v2 < v ? v2 : v;
        }
        if (__all(v >= tgt)) break;
        __builtin_amdgcn_s_sleep(1);
      }
      __builtin_amdgcn_sched_barrier(0);
      // ---- bulk h loads (single shot) + h MFMAs ----
      short8 hregs[KTW][4];
      #pragma unroll
      for (int kt = 0; kt < KTW; ++kt){
        const int kg = (w*KTW + kt) * 32;
        if (kg >= KX){
          #pragma unroll
          for (int mt = 0; mt < 4; ++mt){
            const ull* hp = (const ull*)(hb + (size_t)par*64*U + (size_t)(mt*16 + arow)*U + (kg - KX + kgrp));
            ulonglong2 u;
            u.x = __hip_atomic_load(hp,     __ATOMIC_RELAXED, __HIP_MEMORY_SCOPE_AGENT);
            u.y = __hip_atomic_load(hp + 1, __ATOMIC_RELAXED, __HIP_MEMORY_SCOPE_AGENT);
            hregs[kt][mt] = __builtin_bit_cast(short8, u);
          }
        }
      }
      #pragma unroll
      for (int kt = 0; kt < KTW; ++kt){
        const int kg = (w*KTW + kt) * 32;
        if (kg >= KX){
          #pragma unroll
          for (int mt = 0; mt < 4; ++mt)
            #pragma unroll
            for (int nt = 0; nt < 4; ++nt)
              acc[mt][nt] = __builtin_amdgcn_mfma_f32_16x16x32_bf16(hregs[kt][mt], bfr[kt][nt], acc[mt][nt], 0, 0, 0);
        }
      }
    }

    // ---- D-frag scatter into parity buffer: b128 ----
    #pragma unroll
    for (int mt = 0; mt < 4; ++mt)
      #pragma unroll
      for (int nt = 0; nt < 4; ++nt)
        *(f32x4*)&part[par][w][nt*16 + arow][mt*16 + rquad] = acc[mt][nt];

    // ---- single LDS-only barrier per step ----
    bar_lds();

    // ---- gate phase ----
    f32x4 zg[4];
    #pragma unroll
    for (int g = 0; g < 4; ++g){
      const int cb = g*16 + u_l;
      f32x4 v = *(const f32x4*)&part[par][0][cb][rb];
      #pragma unroll
      for (int ww = 1; ww < 4; ++ww)
        v += *(const f32x4*)&part[par][ww][cb][rb];
      zg[g] = v;
    }

    #pragma unroll
    for (int r = 0; r < 4; ++r){
      float ig = sigm (zg[0][r] + bz[0]);
      float fg = sigm (zg[1][r] + bz[1]);
      float gg = tanh_(zg[2][r] + bz[2]);
      float og = sigm (zg[3][r] + bz[3]);
      float cn = fg * c[r] + ig * gg;
      float hn = og * tanh_(cn);
      bool m  = (t < sz[r]);
      c[r] = m ? cn : c[r];
      float h = m ? hn : hreg[r];
      hreg[r] = h;
      if (s != T - 1)
        __hip_atomic_store(&hb[(size_t)(par ^ 1)*64*U + (size_t)(rb + r)*U + ug],
                           (unsigned short)f2bf(h),
                           __ATOMIC_RELAXED, __HIP_MEMORY_SCOPE_AGENT);
    }

    if (s != T - 1){
      // per-wave publish: drain own VMEM (h sc1 stores -> LLC-visible), flag store.
      __builtin_amdgcn_sched_barrier(0);
      asm volatile("s_waitcnt vmcnt(0)" ::: "memory");
      __builtin_amdgcn_sched_barrier(0);
      if (lane == 0)
        __hip_atomic_store(&flg[(wg*4 + w)*32], (unsigned)(s + 1),
                           __ATOMIC_RELAXED, __HIP_MEMORY_SCOPE_AGENT);
      __builtin_amdgcn_sched_barrier(0);
    }

    // ---- out stores AFTER publish (acks never in the chain) ----
    #pragma unroll
    for (int r = 0; r < 4; ++r){
      const size_t oi = ((size_t)(rb + r)*T + t)*U + ug;
      if constexpr (OBF) ((unsigned short*)outp)[oi] = f2bf(hreg[r]);
      else               ((float*)outp)[oi] = hreg[r];
    }

    // ---- x prefetch for next step ----
    if (s != T - 1){
      const int tn = dir ? t - 1 : t + 1;
      #pragma unroll
      for (int kt = 0; kt < KTW; ++kt){
        const int kg = (w*KTW + kt) * 32;
        if (kg < KX){
          #pragma unroll
          for (int mt = 0; mt < 4; ++mt)
            xreg[kt][mt] = *(const short8*)(xab + ((size_t)((mt*16 + arow)*T + tn))*KX + (kg + kgrp));
        }
      }
    }
  }
}

// ---------------- launch ----------------

extern "C" void kernel_launch(void* const* d_in, const int* in_sizes, int n_in,
                              void* d_out, int out_size, void* d_ws, size_t ws_size,
                              hipStream_t stream){
  const float* x      = (const float*)d_in[0];
  const int*   sizes  = (const int*)  d_in[1];
  const float* enc_kf = (const float*)d_in[2];
  const float* enc_rf = (const float*)d_in[3];
  const float* enc_bf = (const float*)d_in[4];
  const float* enc_kb = (const float*)d_in[5];
  const float* enc_rb = (const float*)d_in[6];
  const float* enc_bb = (const float*)d_in[7];
  const float* dec_kf = (const float*)d_in[8];
  const float* dec_rf = (const float*)d_in[9];
  const float* dec_bf = (const float*)d_in[10];
  const float* dec_kb = (const float*)d_in[11];
  const float* dec_rb = (const float*)d_in[12];
  const float* dec_bb = (const float*)d_in[13];
  float* out = (float*)d_out;
  char*  ws  = (char*)d_ws;

  const size_t o_xbf   = 0;                        // 33,554,432  x bf16 [64][512][512]
  const size_t o_esum  = o_xbf   + 33554432ull;    // 16,777,216  enc fwd+bwd sum bf16
  const size_t o_pBe   = o_esum  + 16777216ull;    //  3,145,728  packed enc [k;r]
  const size_t o_pBd   = o_pBe   + 3145728ull;     //  6,291,456  packed dec [k;r]
  const size_t o_ehf   = o_pBd   + 6291456ull;     // 16,777,216  enc fwd h bf16
  const size_t o_ehb   = o_ehf   + 16777216ull;    // 16,777,216  enc bwd h bf16
  const size_t o_dhb   = o_ehb   + 16777216ull;    // 67,108,864  dec bwd h f32
  const size_t o_hbufe = o_dhb   + 67108864ull;    //    131,072  enc h exchange
  const size_t o_hbufd = o_hbufe + 131072ull;      //    262,144  dec h exchange
  const size_t o_flge  = o_hbufd + 262144ull;      //     16,384  enc per-wave flags (2 dirs)
  const size_t o_flgd  = o_flge  + 16384ull;       //     32,768  dec per-wave flags (2 dirs)
  const size_t total   = o_flgd  + 32768ull;       // ~160.5 MB
  if (ws_size < total) return;

  unsigned short* xbf   = (unsigned short*)(ws + o_xbf);
  unsigned short* esum  = (unsigned short*)(ws + o_esum);
  unsigned short* pBe   = (unsigned short*)(ws + o_pBe);
  unsigned short* pBd   = (unsigned short*)(ws + o_pBd);
  unsigned short* ehf   = (unsigned short*)(ws + o_ehf);
  unsigned short* ehb   = (unsigned short*)(ws + o_ehb);
  float*          dhb   = (float*)(ws + o_dhb);
  unsigned short* hbufe = (unsigned short*)(ws + o_hbufe);
  unsigned short* hbufd = (unsigned short*)(ws + o_hbufd);
  unsigned*       flge  = (unsigned*)(ws + o_flge);
  unsigned*       flgd  = (unsigned*)(ws + o_flgd);

  // zero flags every call (deterministic graph replays); hbuf needs no init
  // (consumers read a slot only after its producing step's flag is seen).
  hipMemsetAsync(ws + o_flge, 0, 16384ull + 32768ull, stream);

  // x -> bf16
  k_f32_to_bf16<<<2048, 256, 0, stream>>>(x, xbf, 64*512*512);

  // pack weights (blocked K split)
  k_pack<<<2048, 256, 0, stream>>>(enc_kf, enc_rf, enc_kb, enc_rb, pBe, 786432, 512, 256);
  k_pack<<<2048, 256, 0, stream>>>(dec_kf, dec_rf, dec_kb, dec_rb, pBd, 1572864, 256, 512);

  // encoder bilstm (fwd 16 WGs + bwd 16 WGs), bf16 outputs
  lstm_rec<512, 256, 16, true><<<32, 256, 0, stream>>>(xbf, pBe, enc_bf, enc_bb, sizes,
                                                       hbufe, flge, ehf, ehb);
  // enc_sum = bf16(hf + hb)
  k_add_bb<<<2048, 256, 0, stream>>>(ehf, ehb, esum, 64*512*256);

  // decoder bilstm: fwd writes d_out f32, bwd to ws
  lstm_rec<256, 512, 32, false><<<64, 256, 0, stream>>>(esum, pBd, dec_bf, dec_bb, sizes,
                                                        hbufd, flgd, out, dhb);
  // d_out += dec bwd
  k_add_f32<<<2048, 256, 0, stream>>>(out, dhb, 64*512*512);
}